// Round 5
// baseline (5830.002 us; speedup 1.0000x reference)
//
#include <hip/hip_runtime.h>
#include <hip/hip_fp16.h>

// Problem constants
#define TT 2048
#define II 1739
#define HN 256
#define H3 768
#define L2E 1.44269504088896f

typedef _Float16 h8 __attribute__((ext_vector_type(8)));
typedef float f4 __attribute__((ext_vector_type(4)));

__device__ __forceinline__ float fast_exp2(float x) {
#if defined(__has_builtin)
#if __has_builtin(__builtin_amdgcn_exp2f)
  return __builtin_amdgcn_exp2f(x);
#else
  return exp2f(x);
#endif
#else
  return exp2f(x);
#endif
}

__device__ __forceinline__ float fast_rcp(float x) {
#if defined(__has_builtin)
#if __has_builtin(__builtin_amdgcn_rcpf)
  return __builtin_amdgcn_rcpf(x);
#else
  return 1.f / x;
#endif
#else
  return 1.f / x;
#endif
}

// C[M,N] = ((A[M,K] @ B[N,K]^T) + bias1[n] + (n < b2lim ? bias2[n] : 0)) * (n < slim ? s_lo : s_hi)
// 64x64 tile, 256 threads, 4x4 micro-tile per thread.
__global__ __launch_bounds__(256) void gemm_abt(
    const float* __restrict__ A, int M, int K,
    const float* __restrict__ B, int N,
    const float* __restrict__ bias1, const float* __restrict__ bias2, int b2lim,
    float s_lo, float s_hi, int slim,
    float* __restrict__ C) {
  __shared__ float As[16][64];
  __shared__ float Bs[16][64];
  const int tid = threadIdx.x;
  const int m0 = blockIdx.y * 64, n0 = blockIdx.x * 64;
  const int lr = tid >> 2;        // 0..63  (row within tile for loads)
  const int lk = (tid & 3) * 4;   // 0,4,8,12
  const int cx = tid & 15, cy = tid >> 4;
  float acc[4][4] = {};

  for (int k0 = 0; k0 < K; k0 += 16) {
#pragma unroll
    for (int i = 0; i < 4; ++i) {
      int k = k0 + lk + i;
      As[lk + i][lr] = (k < K) ? A[(size_t)(m0 + lr) * K + k] : 0.f;
      int bn = n0 + lr;
      Bs[lk + i][lr] = (k < K && bn < N) ? B[(size_t)bn * K + k] : 0.f;
    }
    __syncthreads();
#pragma unroll
    for (int k = 0; k < 16; ++k) {
      float4 av = *(const float4*)&As[k][cy * 4];
      float4 bv = *(const float4*)&Bs[k][cx * 4];
      const float aa[4] = {av.x, av.y, av.z, av.w};
      const float bb[4] = {bv.x, bv.y, bv.z, bv.w};
#pragma unroll
      for (int i = 0; i < 4; ++i)
#pragma unroll
        for (int j = 0; j < 4; ++j) acc[i][j] = fmaf(aa[i], bb[j], acc[i][j]);
    }
    __syncthreads();
  }
#pragma unroll
  for (int i = 0; i < 4; ++i) {
    int m = m0 + cy * 4 + i;
#pragma unroll
    for (int j = 0; j < 4; ++j) {
      int n = n0 + cx * 4 + j;
      if (n < N) {
        float b = bias1 ? bias1[n] : 0.f;
        if (bias2 && n < b2lim) b += bias2[n];
        float s = (n < slim) ? s_lo : s_hi;
        C[(size_t)m * N + n] = (acc[i][j] + b) * s;
      }
    }
  }
}

// Sequential GRU scan on a single CU (1 block, 512 threads = 8 waves).
//
// Rounds 0-4 established: the allocator ALWAYS splits the budget so the
// weight array is AGPR-resident, and VALU (v_dot2) cannot read AGPRs ->
// ~1 v_accvgpr_read per fdot2 == the constant 2x VALU-issue tax measured
// in every round. This round flips it: MFMA reads A/B straight from AGPR.
//
// Matvec via v_mfma_f32_16x16x32_f16 with h REPLICATED across all 16 B
// columns: B[k][n] = h[k] for every n, so lane's B-frag = h[(lane>>4)*8+j]
// (independent of lane&15) = one ds_read_b128 per k-step, no shuffles.
// Wave w owns hidden units [32w, 32w+32) for ALL THREE gates:
//   6 A-fragments (gate g, half hf) x 8 k-steps = 48 MFMA/wave/step,
//   weights = 192 AGPR (stationary), acc = 24 AGPR.
// A-frag (M=16,K=32): lane holds row = lane&15, k = (lane>>4)*8 + j.
// D (16x16): col = lane&15 (all cols identical here), m = (lane>>4)*4+reg.
// Redistribute D -> unit-per-lane via wave-private LDS scratch (writer
// lanes col==0; readers lane<32) -- wave-internal lgkmcnt only, NO block
// barrier. Gates = round-4 fast-exp2 form (passed refcheck); hj stays
// fp32 in-register (lane<32 owns unit u = 32w+lane persistently).
// One block barrier per step (double-buffered f16 h in LDS).
__global__ __attribute__((amdgpu_flat_work_group_size(512, 512)))
__attribute__((amdgpu_waves_per_eu(2, 2))) void gru_seq(
    const float* __restrict__ xp,      // [T, 768], pre-scaled by L2E/2L2E
    const float* __restrict__ Whh,     // [768, 256]
    const float* __restrict__ bhh,     // [768]
    const float* __restrict__ h0,      // [256] or nullptr (zeros)
    float* __restrict__ hs_out,        // [T, 256] or nullptr
    float* __restrict__ hT_out) {      // [256] or nullptr
  __shared__ __align__(16) _Float16 hbuf[2][HN];  // double-buffered h (f16)
  __shared__ __align__(16) float gsc[8][100];     // per-wave gate scratch

  const int tid = threadIdx.x;
  const int lane = tid & 63;
  const int wv = tid >> 6;         // 0..7
  const int col = lane & 15;       // MFMA col / A-row index
  const int kg = lane >> 4;        // 0..3 k-group
  const int u = wv * 32 + lane;    // unit id (valid for lane<32)

  // Load W_hh into 48 stationary A-fragments (f16, pre-scaled for exp2).
  // wfrag[g*2+hf][kk]: rows g*256 + wv*32 + hf*16 + (lane&15), k-chunk kk.
  h8 wfrag[6][8];
#pragma unroll
  for (int g = 0; g < 3; ++g) {
#pragma unroll
    for (int hf = 0; hf < 2; ++hf) {
      const float sc = (g == 2) ? (2.f * L2E) : L2E;
      const int row = g * HN + wv * 32 + hf * 16 + col;
      const float* wr = Whh + (size_t)row * HN + kg * 8;
#pragma unroll
      for (int kk = 0; kk < 8; ++kk) {
        float4 f0 = *(const float4*)(wr + kk * 32);
        float4 f1 = *(const float4*)(wr + kk * 32 + 4);
        h8 v;
        v[0] = (_Float16)(f0.x * sc); v[1] = (_Float16)(f0.y * sc);
        v[2] = (_Float16)(f0.z * sc); v[3] = (_Float16)(f0.w * sc);
        v[4] = (_Float16)(f1.x * sc); v[5] = (_Float16)(f1.y * sc);
        v[6] = (_Float16)(f1.z * sc); v[7] = (_Float16)(f1.w * sc);
        wfrag[g * 2 + hf][kk] = v;
      }
    }
  }

  float hj = 0.f, bhn = 0.f;
  if (lane < 32) {
    hj = h0 ? h0[u] : 0.f;
    bhn = bhh[2 * HN + u] * (2.f * L2E);
    hbuf[0][u] = (_Float16)hj;
  }
  __syncthreads();

  float* gw = &gsc[wv][0];
  const f4 zero4 = {0.f, 0.f, 0.f, 0.f};

  for (int t = 0; t < TT; ++t) {
    // This step's x-projection (issued early; consumed in the gate phase).
    float xr = 0.f, xz = 0.f, xn = 0.f;
    if (lane < 32) {
      const float* xpt = xp + (size_t)t * H3 + u;
      xr = xpt[0];
      xz = xpt[HN];
      xn = xpt[2 * HN];
    }

    // Matvec: 48 MFMAs, weights stationary in AGPR, h broadcast from LDS.
    const _Float16* hc = &hbuf[t & 1][0];
    f4 acc[6];
    {
      h8 b = *(const h8*)&hc[kg * 8];
#pragma unroll
      for (int f = 0; f < 6; ++f)
        acc[f] = __builtin_amdgcn_mfma_f32_16x16x32_f16(wfrag[f][0], b, zero4, 0, 0, 0);
    }
#pragma unroll
    for (int kk = 1; kk < 8; ++kk) {
      h8 b = *(const h8*)&hc[kk * 32 + kg * 8];
#pragma unroll
      for (int f = 0; f < 6; ++f)
        acc[f] = __builtin_amdgcn_mfma_f32_16x16x32_f16(wfrag[f][kk], b, acc[f], 0, 0, 0);
    }

    // Redistribute D -> gsc (writer lanes: col==0; m = kg*4 + reg).
    if (col == 0) {
#pragma unroll
      for (int g = 0; g < 3; ++g)
#pragma unroll
        for (int hf = 0; hf < 2; ++hf)
          *(f4*)&gw[g * 32 + hf * 16 + kg * 4] = acc[g * 2 + hf];
    }

    // Gates on lanes 0..31 (unit u); args pre-scaled by log2e / 2log2e.
    if (lane < 32) {
      float ar = gw[lane];
      float az = gw[32 + lane];
      float an = gw[64 + lane];
      float r = fast_rcp(1.f + fast_exp2(-(xr + ar)));
      float z = fast_rcp(1.f + fast_exp2(-(xz + az)));
      float nv = fmaf(2.f, fast_rcp(1.f + fast_exp2(-fmaf(r, an + bhn, xn))), -1.f);
      hj = fmaf(z, hj - nv, nv);
      hbuf[(t & 1) ^ 1][u] = (_Float16)hj;
      if (hs_out) hs_out[(size_t)t * HN + u] = hj;
    }
    __syncthreads();
  }
  if (hT_out && lane < 32) hT_out[u] = hj;
}

extern "C" void kernel_launch(void* const* d_in, const int* in_sizes, int n_in,
                              void* d_out, int out_size, void* d_ws, size_t ws_size,
                              hipStream_t stream) {
  const float* x     = (const float*)d_in[0];   // [1, 2048, 1739]
  const float* Wih_e = (const float*)d_in[2];   // [768, 1739]
  const float* Whh_e = (const float*)d_in[3];   // [768, 256]
  const float* bih_e = (const float*)d_in[4];   // [768]
  const float* bhh_e = (const float*)d_in[5];   // [768]
  const float* Wih_d = (const float*)d_in[6];
  const float* Whh_d = (const float*)d_in[7];
  const float* bih_d = (const float*)d_in[8];
  const float* bhh_d = (const float*)d_in[9];
  const float* Wout  = (const float*)d_in[10];  // [1739, 256]
  const float* bout  = (const float*)d_in[11];  // [1739]
  float* out = (float*)d_out;                   // [2048, 1, 1739]

  float* ws = (float*)d_ws;
  float* xpe  = ws;                              // 2048*768
  float* xpd  = xpe + (size_t)TT * H3;           // 2048*768
  float* hs   = xpd + (size_t)TT * H3;           // 2048*256
  float* henc = hs + (size_t)TT * HN;            // 256

  dim3 blk(256);
  // x-projections, pre-scaled for exp2-based gates:
  //   rows [0,512) (r,z): (x@W^T + bih + bhh) * log2e
  //   rows [512,768) (n): (x@W^T + bih) * 2log2e   (bhh n-part in-gate)
  gemm_abt<<<dim3(12, 32), blk, 0, stream>>>(x, TT, II, Wih_e, H3, bih_e, bhh_e, 2 * HN,
                                             L2E, 2.f * L2E, 2 * HN, xpe);
  gemm_abt<<<dim3(12, 32), blk, 0, stream>>>(x, TT, II, Wih_d, H3, bih_d, bhh_d, 2 * HN,
                                             L2E, 2.f * L2E, 2 * HN, xpd);
  // encoder scan -> henc
  gru_seq<<<1, 512, 0, stream>>>(xpe, Whh_e, bhh_e, nullptr, nullptr, henc);
  // decoder scan -> hs
  gru_seq<<<1, 512, 0, stream>>>(xpd, Whh_d, bhh_d, henc, hs, nullptr);
  // output projection (unscaled)
  gemm_abt<<<dim3(28, 32), blk, 0, stream>>>(hs, TT, HN, Wout, II, bout, nullptr, 0,
                                             1.f, 1.f, 0, out);
}

// Round 6
// 5277.548 us; speedup vs baseline: 1.1047x; 1.1047x over previous
//
#include <hip/hip_runtime.h>
#include <hip/hip_fp16.h>

// Problem constants
#define TT 2048
#define II 1739
#define HN 256
#define H3 768
#define L2E 1.44269504088896f

typedef _Float16 h2 __attribute__((ext_vector_type(2)));

__device__ __forceinline__ float fdot2(h2 a, h2 b, float c) {
#if defined(__has_builtin)
#if __has_builtin(__builtin_amdgcn_fdot2)
  return __builtin_amdgcn_fdot2(a, b, c, false);
#else
  return fmaf((float)a[0], (float)b[0], fmaf((float)a[1], (float)b[1], c));
#endif
#else
  return fmaf((float)a[0], (float)b[0], fmaf((float)a[1], (float)b[1], c));
#endif
}

__device__ __forceinline__ float fast_exp2(float x) {
#if defined(__has_builtin)
#if __has_builtin(__builtin_amdgcn_exp2f)
  return __builtin_amdgcn_exp2f(x);
#else
  return exp2f(x);
#endif
#else
  return exp2f(x);
#endif
}

__device__ __forceinline__ float fast_rcp(float x) {
#if defined(__has_builtin)
#if __has_builtin(__builtin_amdgcn_rcpf)
  return __builtin_amdgcn_rcpf(x);
#else
  return 1.f / x;
#endif
#else
  return 1.f / x;
#endif
}

template <int CTRL>
__device__ __forceinline__ float dpp_qperm(float v) {
  int r = __builtin_amdgcn_update_dpp(0, __builtin_bit_cast(int, v), CTRL, 0xF, 0xF, true);
  return __builtin_bit_cast(float, r);
}

// C[M,N] = ((A[M,K] @ B[N,K]^T) + bias1[n] + (n < b2lim ? bias2[n] : 0)) * (n < slim ? s_lo : s_hi)
// 64x64 tile, 256 threads, 4x4 micro-tile per thread.
__global__ __launch_bounds__(256) void gemm_abt(
    const float* __restrict__ A, int M, int K,
    const float* __restrict__ B, int N,
    const float* __restrict__ bias1, const float* __restrict__ bias2, int b2lim,
    float s_lo, float s_hi, int slim,
    float* __restrict__ C) {
  __shared__ float As[16][64];
  __shared__ float Bs[16][64];
  const int tid = threadIdx.x;
  const int m0 = blockIdx.y * 64, n0 = blockIdx.x * 64;
  const int lr = tid >> 2;        // 0..63  (row within tile for loads)
  const int lk = (tid & 3) * 4;   // 0,4,8,12
  const int cx = tid & 15, cy = tid >> 4;
  float acc[4][4] = {};

  for (int k0 = 0; k0 < K; k0 += 16) {
#pragma unroll
    for (int i = 0; i < 4; ++i) {
      int k = k0 + lk + i;
      As[lk + i][lr] = (k < K) ? A[(size_t)(m0 + lr) * K + k] : 0.f;
      int bn = n0 + lr;
      Bs[lk + i][lr] = (k < K && bn < N) ? B[(size_t)bn * K + k] : 0.f;
    }
    __syncthreads();
#pragma unroll
    for (int k = 0; k < 16; ++k) {
      float4 av = *(const float4*)&As[k][cy * 4];
      float4 bv = *(const float4*)&Bs[k][cx * 4];
      const float aa[4] = {av.x, av.y, av.z, av.w};
      const float bb[4] = {bv.x, bv.y, bv.z, bv.w};
#pragma unroll
      for (int i = 0; i < 4; ++i)
#pragma unroll
        for (int j = 0; j < 4; ++j) acc[i][j] = fmaf(aa[i], bb[j], acc[i][j]);
    }
    __syncthreads();
  }
#pragma unroll
  for (int i = 0; i < 4; ++i) {
    int m = m0 + cy * 4 + i;
#pragma unroll
    for (int j = 0; j < 4; ++j) {
      int n = n0 + cx * 4 + j;
      if (n < N) {
        float b = bias1 ? bias1[n] : 0.f;
        if (bias2 && n < b2lim) b += bias2[n];
        float s = (n < slim) ? s_lo : s_hi;
        C[(size_t)m * N + n] = (acc[i][j] + b) * s;
      }
    }
  }
}

// Sequential GRU scan on a single CU (1 block, 1024 threads = 16 waves,
// 4 waves/SIMD pinned via waves_per_eu(4,4) -> 128-VGPR budget).
//
// Register-budget design (the lesson of rounds 0-5): per-wave weight
// footprint must fit the ARCH VGPR file. 16 waves -> 96 dwords of f16
// weights/thread + ~25 working set ~= 120 < 128. 4 waves/SIMD x 128 =
// 512 = the whole physical file. No AGPRs -> no v_accvgpr tax (the
// constant ~770 cy/step in every earlier round), no spill.
//
// Structure (round-4 wins ported):
//  - Quad q (= wv*16 + lane>>2, q in [0,256)) owns hidden unit q and
//    computes all three gate rows {q, q+256, q+512}; lane kc = lane&3
//    covers k-chunk [64kc, 64kc+64). After the quad DPP butterfly all
//    4 lanes hold hr/hz/hn -> gates computed locally, in-register.
//  - Double-buffered f16 h in LDS -> ONE barrier per step.
//  - exp2-form gates with pre-scaled arguments (xp GEMM scales r,z rows
//    by log2e, n rows by 2log2e; W_hh / bhn scaled at load).
//  - x-prefetch one step ahead in registers: step t issues the loads for
//    t+1 and consumes t's values -> global-load latency (~200-900 cy)
//    fully off the per-step critical path. The t+1 over-read at t=2047
//    lands in the adjacent workspace buffer (allocated, unused).
//
// hbuf layout (per buffer, 160 dwords): h (256 f16 = 128 dwords) in 4
// k-chunks of 32 dwords at stride 40 -> the 4 distinct per-quad b128
// read addresses hit disjoint bank groups (0 conflicts, verified r1-r4).
// Gate write: lane kc==0 of quad q writes ds_write_b16 at chunk q>>6,
// dword (q&63)>>1, half q&1 -> 16 lanes to 8 consecutive dwords = 2-way
// (free, m136).
__global__ __attribute__((amdgpu_flat_work_group_size(1024, 1024)))
__attribute__((amdgpu_waves_per_eu(4, 4))) void gru_seq(
    const float* __restrict__ xp,      // [T, 768], pre-scaled by L2E/2L2E
    const float* __restrict__ Whh,     // [768, 256]
    const float* __restrict__ bhh,     // [768]
    const float* __restrict__ h0,      // [256] or nullptr (zeros)
    float* __restrict__ hs_out,        // [T, 256] or nullptr
    float* __restrict__ hT_out) {      // [256] or nullptr
  __shared__ __align__(16) uint hbufd[2][160];

  const int tid = threadIdx.x;
  const int lane = tid & 63;
  const int wv = tid >> 6;              // 0..15
  const int kc = lane & 3;              // k-chunk [64*kc, 64*kc+64)
  const int q = wv * 16 + (lane >> 2);  // 0..255: owned hidden unit

  // wreg[gg]: gate row gg*256+q, k-chunk kc, f16 pairs pre-scaled for exp2.
  h2 wreg[3][32];
#pragma unroll
  for (int gg = 0; gg < 3; ++gg) {
    const float sc = (gg == 2) ? (2.f * L2E) : L2E;
    const float* wr = Whh + (size_t)(gg * HN + q) * HN + kc * 64;
#pragma unroll
    for (int p = 0; p < 32; ++p) {
      float2 f = *(const float2*)(wr + 2 * p);
      wreg[gg][p] = h2{(_Float16)(f.x * sc), (_Float16)(f.y * sc)};
    }
  }

  float hj = h0 ? h0[q] : 0.f;                      // all 4 quad lanes hold hj
  const float bhn = bhh[2 * HN + q] * (2.f * L2E);

  if (tid < 128) {
    float a = h0 ? h0[2 * tid] : 0.f;
    float b = h0 ? h0[2 * tid + 1] : 0.f;
    h2 pv = h2{(_Float16)a, (_Float16)b};
    hbufd[0][(tid >> 5) * 40 + (tid & 31)] = __builtin_bit_cast(uint, pv);
  }
  __syncthreads();

  // f16 write slot for unit q (byte address halves handled via pointer).
  _Float16* hwr0 = (_Float16*)&hbufd[0][(q >> 6) * 40 + ((q & 63) >> 1)];
  _Float16* hwr1 = (_Float16*)&hbufd[1][(q >> 6) * 40 + ((q & 63) >> 1)];
  const int hlo = q & 1;

  // x-prefetch registers (current step's values; next loaded during step).
  const float* xq = xp + q;
  float xr = xq[0], xz = xq[HN], xn = xq[2 * HN];

  for (int t = 0; t < TT; ++t) {
    // Issue next step's x loads now; consumed after the next barrier.
    const float* xqn = xq + (size_t)(t + 1) * H3;
    float xr_n = xqn[0];
    float xz_n = xqn[HN];
    float xn_n = xqn[2 * HN];

    // Matvec: 3 rows x 64 k per thread (f16 dot2, fp32 accumulate).
    const uint* hb = &hbufd[t & 1][kc * 40];
    float a0 = 0.f, a1 = 0.f, a2 = 0.f;
#pragma unroll
    for (int qq = 0; qq < 8; ++qq) {
      uint4 v = *(const uint4*)&hb[qq * 4];
      uint hwv[4] = {v.x, v.y, v.z, v.w};
#pragma unroll
      for (int p = 0; p < 4; ++p) {
        h2 hp = __builtin_bit_cast(h2, hwv[p]);
        a0 = fdot2(wreg[0][qq * 4 + p], hp, a0);
        a1 = fdot2(wreg[1][qq * 4 + p], hp, a1);
        a2 = fdot2(wreg[2][qq * 4 + p], hp, a2);
      }
    }

    // Quad butterfly: all 4 lanes end with full k-sums (bit-identical).
    a0 += dpp_qperm<0xB1>(a0); a0 += dpp_qperm<0x4E>(a0);
    a1 += dpp_qperm<0xB1>(a1); a1 += dpp_qperm<0x4E>(a1);
    a2 += dpp_qperm<0xB1>(a2); a2 += dpp_qperm<0x4E>(a2);

    // Gates (all quad lanes redundantly; args pre-scaled by log2e/2log2e).
    float r = fast_rcp(1.f + fast_exp2(-(xr + a0)));
    float z = fast_rcp(1.f + fast_exp2(-(xz + a1)));
    float nv = fmaf(2.f, fast_rcp(1.f + fast_exp2(-fmaf(r, a2 + bhn, xn))), -1.f);
    hj = fmaf(z, hj - nv, nv);

    if (kc == 0) {
      _Float16* hw = (t & 1) ? hwr0 : hwr1;  // write buffer (t+1)&1
      hw[hlo] = (_Float16)hj;
      if (hs_out) hs_out[(size_t)t * HN + q] = hj;
    }
    xr = xr_n; xz = xz_n; xn = xn_n;
    __syncthreads();
  }
  if (hT_out && kc == 0) hT_out[q] = hj;
}

extern "C" void kernel_launch(void* const* d_in, const int* in_sizes, int n_in,
                              void* d_out, int out_size, void* d_ws, size_t ws_size,
                              hipStream_t stream) {
  const float* x     = (const float*)d_in[0];   // [1, 2048, 1739]
  const float* Wih_e = (const float*)d_in[2];   // [768, 1739]
  const float* Whh_e = (const float*)d_in[3];   // [768, 256]
  const float* bih_e = (const float*)d_in[4];   // [768]
  const float* bhh_e = (const float*)d_in[5];   // [768]
  const float* Wih_d = (const float*)d_in[6];
  const float* Whh_d = (const float*)d_in[7];
  const float* bih_d = (const float*)d_in[8];
  const float* bhh_d = (const float*)d_in[9];
  const float* Wout  = (const float*)d_in[10];  // [1739, 256]
  const float* bout  = (const float*)d_in[11];  // [1739]
  float* out = (float*)d_out;                   // [2048, 1, 1739]

  float* ws = (float*)d_ws;
  float* xpe  = ws;                              // 2048*768
  float* xpd  = xpe + (size_t)TT * H3;           // 2048*768  (xpe over-read pad)
  float* hs   = xpd + (size_t)TT * H3;           // 2048*256  (xpd over-read pad)
  float* henc = hs + (size_t)TT * HN;            // 256

  dim3 blk(256);
  // x-projections, pre-scaled for exp2-based gates:
  //   rows [0,512) (r,z): (x@W^T + bih + bhh) * log2e
  //   rows [512,768) (n): (x@W^T + bih) * 2log2e   (bhh n-part in-gate)
  gemm_abt<<<dim3(12, 32), blk, 0, stream>>>(x, TT, II, Wih_e, H3, bih_e, bhh_e, 2 * HN,
                                             L2E, 2.f * L2E, 2 * HN, xpe);
  gemm_abt<<<dim3(12, 32), blk, 0, stream>>>(x, TT, II, Wih_d, H3, bih_d, bhh_d, 2 * HN,
                                             L2E, 2.f * L2E, 2 * HN, xpd);
  // encoder scan -> henc
  gru_seq<<<1, 1024, 0, stream>>>(xpe, Whh_e, bhh_e, nullptr, nullptr, henc);
  // decoder scan -> hs
  gru_seq<<<1, 1024, 0, stream>>>(xpd, Whh_d, bhh_d, henc, hs, nullptr);
  // output projection (unscaled)
  gemm_abt<<<dim3(28, 32), blk, 0, stream>>>(hs, TT, HN, Wout, II, bout, nullptr, 0,
                                             1.f, 1.f, 0, out);
}